// Round 1
// baseline (275.139 us; speedup 1.0000x reference)
//
#include <hip/hip_runtime.h>
#include <hip/hip_bf16.h>

// Problem dims (fixed by reference)
#define BATCH 128
#define PIX   196
#define EDIM  2048
#define DDIM  512
#define ADIM  512
#define MTOT  (BATCH*PIX)   // 25088

typedef __attribute__((ext_vector_type(8))) short short8;
typedef __attribute__((ext_vector_type(4))) float f32x4;

__device__ __forceinline__ unsigned short f2bf(float f) {
    union { float f; unsigned int u; } c; c.f = f;
    unsigned int u = c.u;
    u += 0x7fffu + ((u >> 16) & 1u);   // round-to-nearest-even
    return (unsigned short)(u >> 16);
}

// ---------------------------------------------------------------------------
// Kernel 0: transpose + convert W_enc [K=2048][A=512] fp32 -> WT [A=512][K=2048] bf16
// ---------------------------------------------------------------------------
__global__ __launch_bounds__(256) void transpose_wenc(const float* __restrict__ Wenc,
                                                      unsigned short* __restrict__ WT) {
    __shared__ unsigned short t[64][72];   // +8 pad
    const int k0 = blockIdx.x * 64;        // 32 blocks along K
    const int n0 = blockIdx.y * 64;        // 8 blocks along A
    const int tid = threadIdx.x;
    {
        const int kl = tid >> 4;           // 0..15
        const int n4 = (tid & 15) * 4;
        #pragma unroll
        for (int it = 0; it < 4; it++) {
            int k = kl + it * 16;
            float4 v = *(const float4*)&Wenc[(size_t)(k0 + k) * ADIM + n0 + n4];
            t[n4 + 0][k] = f2bf(v.x);
            t[n4 + 1][k] = f2bf(v.y);
            t[n4 + 2][k] = f2bf(v.z);
            t[n4 + 3][k] = f2bf(v.w);
        }
    }
    __syncthreads();
    {
        const int nl = tid >> 4;
        const int k4 = (tid & 15) * 4;
        #pragma unroll
        for (int it = 0; it < 4; it++) {
            int n = nl + it * 16;
            ushort4 o;
            o.x = t[n][k4 + 0]; o.y = t[n][k4 + 1];
            o.z = t[n][k4 + 2]; o.w = t[n][k4 + 3];
            *(ushort4*)&WT[(size_t)(n0 + n) * EDIM + k0 + k4] = o;
        }
    }
}

// ---------------------------------------------------------------------------
// Kernel 1: bias[b][a] = sum_d dec[b][d]*Wdec[d][a] + b_dec[a] + b_enc[a]
// 32 blocks x 256 threads; each block handles 4 batches, each thread 2 a-cols
// ---------------------------------------------------------------------------
__global__ __launch_bounds__(256) void bias_kernel(const float* __restrict__ dec,
                                                   const float* __restrict__ Wdec,
                                                   const float* __restrict__ b_enc,
                                                   const float* __restrict__ b_dec,
                                                   float* __restrict__ bias) {
    __shared__ float ds[4 * DDIM];
    const int b0 = blockIdx.x * 4;
    for (int i = threadIdx.x; i < 4 * DDIM; i += 256)
        ds[i] = dec[(size_t)b0 * DDIM + i];
    __syncthreads();
    const int a0 = threadIdx.x * 2;
    float acc0[4] = {0.f, 0.f, 0.f, 0.f};
    float acc1[4] = {0.f, 0.f, 0.f, 0.f};
    for (int d = 0; d < DDIM; d++) {
        float2 w = *(const float2*)&Wdec[(size_t)d * ADIM + a0];
        #pragma unroll
        for (int bi = 0; bi < 4; bi++) {
            float dv = ds[bi * DDIM + d];
            acc0[bi] += dv * w.x;
            acc1[bi] += dv * w.y;
        }
    }
    float be0 = b_enc[a0] + b_dec[a0];
    float be1 = b_enc[a0 + 1] + b_dec[a0 + 1];
    #pragma unroll
    for (int bi = 0; bi < 4; bi++) {
        bias[(size_t)(b0 + bi) * ADIM + a0]     = acc0[bi] + be0;
        bias[(size_t)(b0 + bi) * ADIM + a0 + 1] = acc1[bi] + be1;
    }
}

// ---------------------------------------------------------------------------
// Kernel 2: fused att1 GEMM + relu + dot(W_full) -> att[m] (atomic)
// C tile 128x128, 4 waves (2x2 of 64x64), K_TILE=64, mfma 16x16x32 bf16
// A = enc (fp32->bf16 on the fly), B = WT (bf16, [A][K] so both read K-contig)
// ---------------------------------------------------------------------------
#define SWZA(r, kel) ((((r) * 64 + (kel)) * 2) ^ (((r) & 7) << 4))

__global__ __launch_bounds__(256) void gemm_att(const float* __restrict__ enc,
                                                const unsigned short* __restrict__ WT,
                                                const float* __restrict__ bias,
                                                const float* __restrict__ Wfull,
                                                float* __restrict__ att) {
    __shared__ __align__(16) char ldsA[128 * 64 * 2];
    __shared__ __align__(16) char ldsB[128 * 64 * 2];

    const int bid = blockIdx.x;
    const int m0 = (bid >> 2) * 128;
    const int n0 = (bid & 3) * 128;
    const int tid = threadIdx.x;
    const int lane = tid & 63;
    const int wid = tid >> 6;
    const int wm = wid >> 1, wn = wid & 1;
    const int cif = lane & 15;         // col-in-frag
    const int rgrp = lane >> 4;        // 0..3

    f32x4 acc[4][4] = {};

    for (int kt = 0; kt < EDIM / 64; kt++) {
        __syncthreads();
        // stage A: 128 rows x 64 k, fp32 -> bf16
        #pragma unroll
        for (int cc = 0; cc < 4; cc++) {
            int idx = tid + cc * 256;
            int r = idx >> 3, c8 = (idx & 7) << 3;
            const float* g = enc + (size_t)(m0 + r) * EDIM + kt * 64 + c8;
            float4 x = *(const float4*)g;
            float4 y = *(const float4*)(g + 4);
            short8 v;
            v[0] = (short)f2bf(x.x); v[1] = (short)f2bf(x.y);
            v[2] = (short)f2bf(x.z); v[3] = (short)f2bf(x.w);
            v[4] = (short)f2bf(y.x); v[5] = (short)f2bf(y.y);
            v[6] = (short)f2bf(y.z); v[7] = (short)f2bf(y.w);
            *(short8*)(ldsA + SWZA(r, c8)) = v;
        }
        // stage B: 128 a-rows x 64 k, already bf16, K-contiguous
        #pragma unroll
        for (int cc = 0; cc < 4; cc++) {
            int idx = tid + cc * 256;
            int nl = idx >> 3, k8 = (idx & 7) << 3;
            short8 v = *(const short8*)(WT + (size_t)(n0 + nl) * EDIM + kt * 64 + k8);
            *(short8*)(ldsB + SWZA(nl, k8)) = v;
        }
        __syncthreads();
        #pragma unroll
        for (int ks = 0; ks < 2; ks++) {
            const int kq = ks * 32 + rgrp * 8;
            short8 a[4], b[4];
            #pragma unroll
            for (int i = 0; i < 4; i++) {
                int rr = wm * 64 + i * 16 + cif;
                a[i] = *(const short8*)(ldsA + SWZA(rr, kq));
            }
            #pragma unroll
            for (int j = 0; j < 4; j++) {
                int nn = wn * 64 + j * 16 + cif;
                b[j] = *(const short8*)(ldsB + SWZA(nn, kq));
            }
            #pragma unroll
            for (int i = 0; i < 4; i++)
                #pragma unroll
                for (int j = 0; j < 4; j++)
                    acc[i][j] = __builtin_amdgcn_mfma_f32_16x16x32_bf16(a[i], b[j], acc[i][j], 0, 0, 0);
        }
    }

    // Epilogue: relu(acc + bias[b][a]) * Wfull[a], reduce over a, atomicAdd to att
    __syncthreads();
    float* biasT = (float*)ldsA;   // reuse LDS: [2][128]
    const int bfirst = m0 / PIX;
    {
        int bb = tid >> 7, aa = tid & 127;
        int bidx = bfirst + bb;
        if (bidx > BATCH - 1) bidx = BATCH - 1;
        biasT[bb * 128 + aa] = bias[(size_t)bidx * ADIM + n0 + aa];
    }
    __syncthreads();

    float wf[4];
    #pragma unroll
    for (int j = 0; j < 4; j++)
        wf[j] = Wfull[n0 + wn * 64 + j * 16 + cif];

    #pragma unroll
    for (int i = 0; i < 4; i++) {
        #pragma unroll
        for (int r = 0; r < 4; r++) {
            int m = m0 + wm * 64 + i * 16 + rgrp * 4 + r;
            int bb = (m / PIX) - bfirst;
            float s = 0.f;
            #pragma unroll
            for (int j = 0; j < 4; j++) {
                float v = acc[i][j][r] + biasT[bb * 128 + wn * 64 + j * 16 + cif];
                s += fmaxf(v, 0.f) * wf[j];
            }
            s += __shfl_xor(s, 1);
            s += __shfl_xor(s, 2);
            s += __shfl_xor(s, 4);
            s += __shfl_xor(s, 8);
            if (cif == 0) atomicAdd(&att[m], s);
        }
    }
}

// ---------------------------------------------------------------------------
// Kernel 3: softmax over p (b_full is a constant shift -> cancels in softmax)
// ---------------------------------------------------------------------------
__global__ __launch_bounds__(256) void softmax_kernel(const float* __restrict__ att,
                                                      float* __restrict__ alpha) {
    const int b = blockIdx.x;
    const int tid = threadIdx.x;
    const int lane = tid & 63, wid = tid >> 6;
    __shared__ float wred[4];

    float x = (tid < PIX) ? att[(size_t)b * PIX + tid] : -1e30f;
    float m = x;
    #pragma unroll
    for (int off = 32; off >= 1; off >>= 1) m = fmaxf(m, __shfl_xor(m, off));
    if (lane == 0) wred[wid] = m;
    __syncthreads();
    float gm = fmaxf(fmaxf(wred[0], wred[1]), fmaxf(wred[2], wred[3]));
    __syncthreads();

    float e = (tid < PIX) ? __expf(x - gm) : 0.f;
    float s = e;
    #pragma unroll
    for (int off = 32; off >= 1; off >>= 1) s += __shfl_xor(s, off);
    if (lane == 0) wred[wid] = s;
    __syncthreads();
    float gs = wred[0] + wred[1] + wred[2] + wred[3];

    if (tid < PIX) alpha[(size_t)b * PIX + tid] = e / gs;
}

// ---------------------------------------------------------------------------
// Kernel 4: out[b][e] = sum_p enc[b][p][e] * alpha[b][p]
// 2 blocks per batch (e-halves), 256 threads x float4
// ---------------------------------------------------------------------------
__global__ __launch_bounds__(256) void weighted_kernel(const float* __restrict__ enc,
                                                       const float* __restrict__ alpha,
                                                       float* __restrict__ out) {
    const int b = blockIdx.x >> 1;
    const int half = blockIdx.x & 1;
    const int tid = threadIdx.x;
    __shared__ float al[PIX];
    if (tid < PIX) al[tid] = alpha[(size_t)b * PIX + tid];
    __syncthreads();

    const int e = half * 1024 + tid * 4;
    const float4* src = (const float4*)(enc + (size_t)b * PIX * EDIM + e);
    float ax = 0.f, ay = 0.f, az = 0.f, aw = 0.f;
    #pragma unroll 4
    for (int p = 0; p < PIX; p++) {
        float av = al[p];
        float4 v = src[(size_t)p * (EDIM / 4)];
        ax += av * v.x; ay += av * v.y; az += av * v.z; aw += av * v.w;
    }
    float4 o; o.x = ax; o.y = ay; o.z = az; o.w = aw;
    *(float4*)&out[(size_t)b * EDIM + e] = o;
}

// ---------------------------------------------------------------------------
extern "C" void kernel_launch(void* const* d_in, const int* in_sizes, int n_in,
                              void* d_out, int out_size, void* d_ws, size_t ws_size,
                              hipStream_t stream) {
    const float* enc   = (const float*)d_in[0];   // [128,196,2048]
    const float* dec   = (const float*)d_in[1];   // [128,512]
    const float* Wenc  = (const float*)d_in[2];   // [2048,512]
    const float* benc  = (const float*)d_in[3];   // [512]
    const float* Wdec  = (const float*)d_in[4];   // [512,512]
    const float* bdec  = (const float*)d_in[5];   // [512]
    const float* Wfull = (const float*)d_in[6];   // [512]
    // d_in[7] = b_full: constant shift, cancels in softmax

    float* out_awe   = (float*)d_out;                       // [128,2048]
    float* out_alpha = (float*)d_out + BATCH * EDIM;        // [128,196]

    char* ws = (char*)d_ws;
    unsigned short* WT = (unsigned short*)ws;                       // 2 MB bf16 [512][2048]
    float* bias = (float*)(ws + (size_t)ADIM * EDIM * 2);           // 256 KB [128][512]
    float* att  = (float*)(ws + (size_t)ADIM * EDIM * 2 + (size_t)BATCH * ADIM * 4); // 100 KB

    transpose_wenc<<<dim3(EDIM / 64, ADIM / 64), 256, 0, stream>>>(Wenc, WT);
    bias_kernel<<<BATCH / 4, 256, 0, stream>>>(dec, Wdec, benc, bdec, bias);
    hipMemsetAsync(att, 0, (size_t)MTOT * 4, stream);
    gemm_att<<<(MTOT / 128) * 4, 256, 0, stream>>>(enc, WT, bias, Wfull, att);
    softmax_kernel<<<BATCH, 256, 0, stream>>>(att, out_alpha);
    weighted_kernel<<<BATCH * 2, 256, 0, stream>>>(enc, out_alpha, out_awe);
}

// Round 2
// 190.058 us; speedup vs baseline: 1.4477x; 1.4477x over previous
//
#include <hip/hip_runtime.h>
#include <hip/hip_bf16.h>

// Problem dims (fixed by reference)
#define BATCH 128
#define PIX   196
#define EDIM  2048
#define DDIM  512
#define ADIM  512
#define MTOT  (BATCH*PIX)   // 25088
#define BK    32
#define NK    (EDIM/BK)     // 64

typedef __attribute__((ext_vector_type(8))) short short8;
typedef __attribute__((ext_vector_type(4))) float f32x4;

__device__ __forceinline__ unsigned short f2bf(float f) {
    union { float f; unsigned int u; } c; c.f = f;
    unsigned int u = c.u;
    u += 0x7fffu + ((u >> 16) & 1u);   // round-to-nearest-even
    return (unsigned short)(u >> 16);
}

#define GLOAD16(gp, lp) __builtin_amdgcn_global_load_lds( \
    (const __attribute__((address_space(1))) void*)(gp),  \
    (__attribute__((address_space(3))) void*)(lp), 16, 0, 0)

__device__ __forceinline__ void sync_lgkm() {
    asm volatile("s_waitcnt lgkmcnt(0)" ::: "memory");
    __builtin_amdgcn_s_barrier();
    asm volatile("" ::: "memory");
}

// ---------------------------------------------------------------------------
// Kernel 0: transpose + convert W_enc [K=2048][A=512] fp32 -> WT [A=512][K=2048] bf16
// ---------------------------------------------------------------------------
__global__ __launch_bounds__(256) void transpose_wenc(const float* __restrict__ Wenc,
                                                      unsigned short* __restrict__ WT) {
    __shared__ unsigned short t[64][72];   // +8 pad
    const int k0 = blockIdx.x * 64;
    const int n0 = blockIdx.y * 64;
    const int tid = threadIdx.x;
    {
        const int kl = tid >> 4;
        const int n4 = (tid & 15) * 4;
        #pragma unroll
        for (int it = 0; it < 4; it++) {
            int k = kl + it * 16;
            float4 v = *(const float4*)&Wenc[(size_t)(k0 + k) * ADIM + n0 + n4];
            t[n4 + 0][k] = f2bf(v.x);
            t[n4 + 1][k] = f2bf(v.y);
            t[n4 + 2][k] = f2bf(v.z);
            t[n4 + 3][k] = f2bf(v.w);
        }
    }
    __syncthreads();
    {
        const int nl = tid >> 4;
        const int k4 = (tid & 15) * 4;
        #pragma unroll
        for (int it = 0; it < 4; it++) {
            int n = nl + it * 16;
            ushort4 o;
            o.x = t[n][k4 + 0]; o.y = t[n][k4 + 1];
            o.z = t[n][k4 + 2]; o.w = t[n][k4 + 3];
            *(ushort4*)&WT[(size_t)(n0 + n) * EDIM + k0 + k4] = o;
        }
    }
}

// ---------------------------------------------------------------------------
// Kernel 1: bias[b][a] = sum_d dec[b][d]*Wdec[d][a] + b_dec[a] + b_enc[a]
// ---------------------------------------------------------------------------
__global__ __launch_bounds__(256) void bias_kernel(const float* __restrict__ dec,
                                                   const float* __restrict__ Wdec,
                                                   const float* __restrict__ b_enc,
                                                   const float* __restrict__ b_dec,
                                                   float* __restrict__ bias) {
    __shared__ float ds[4 * DDIM];
    const int b0 = blockIdx.x * 4;
    for (int i = threadIdx.x; i < 4 * DDIM; i += 256)
        ds[i] = dec[(size_t)b0 * DDIM + i];
    __syncthreads();
    const int a0 = threadIdx.x * 2;
    float acc0[4] = {0.f, 0.f, 0.f, 0.f};
    float acc1[4] = {0.f, 0.f, 0.f, 0.f};
    for (int d = 0; d < DDIM; d++) {
        float2 w = *(const float2*)&Wdec[(size_t)d * ADIM + a0];
        #pragma unroll
        for (int bi = 0; bi < 4; bi++) {
            float dv = ds[bi * DDIM + d];
            acc0[bi] += dv * w.x;
            acc1[bi] += dv * w.y;
        }
    }
    float be0 = b_enc[a0] + b_dec[a0];
    float be1 = b_enc[a0 + 1] + b_dec[a0 + 1];
    #pragma unroll
    for (int bi = 0; bi < 4; bi++) {
        bias[(size_t)(b0 + bi) * ADIM + a0]     = acc0[bi] + be0;
        bias[(size_t)(b0 + bi) * ADIM + a0 + 1] = acc1[bi] + be1;
    }
}

// ---------------------------------------------------------------------------
// Kernel 2: fused att1 GEMM + relu + dot(W_full) -> att[m]
// Tile 128M x 512N x 32K. 8 waves (2M x 4N), wave tile 64x128.
// LDS chunk-major [BK/8][rows][16B]: dense, conflict-free, gload_lds-compatible.
// B: global_load_lds 3-deep ring; A: fp32->bf16 reg-staged 2-deep (T14 split).
// ---------------------------------------------------------------------------
__global__ __launch_bounds__(512, 2) void gemm_att(const float* __restrict__ enc,
                                                   const unsigned short* __restrict__ WT,
                                                   const float* __restrict__ bias,
                                                   const float* __restrict__ Wfull,
                                                   float* __restrict__ att) {
    __shared__ __align__(16) char ldsA[2][8192];    // [chunk 0..3][row 0..127][16B]
    __shared__ __align__(16) char ldsB[3][32768];   // [chunk 0..3][n 0..511][16B]
    __shared__ float red[4][128];

    const int tid  = threadIdx.x;
    const int lane = tid & 63;
    const int wid  = tid >> 6;          // 0..7
    const int wm   = wid >> 2;          // 0..1
    const int wn   = wid & 3;           // 0..3
    const int cif  = lane & 15;
    const int rgrp = lane >> 4;
    const int m0   = blockIdx.x * 128;

    // A staging: thread -> (row = tid>>2, chunk = tid&3), 8 floats -> 8 bf16
    const float* pA = enc + (size_t)(m0 + (tid >> 2)) * EDIM + (tid & 3) * 8;
    const unsigned aWoff = (unsigned)((tid & 3) * 2048 + (tid >> 2) * 16);
    // B staging via gload_lds: wave granule base = wid*256, 4 calls x 64 lanes
    const char* pB = (const char*)(WT + (size_t)((wid & 1) * 256 + lane) * EDIM + (wid >> 1) * 8);
    const unsigned bgOff = (unsigned)(wid * 4096);

    char* aR  = ldsA[0];
    char* aW  = ldsA[1];
    char* bR  = ldsB[0];
    char* bN1 = ldsB[1];
    char* bN2 = ldsB[2];

    f32x4 acc[4][8] = {};
    float4 rg[2][2];

    // ---- prologue: B(0), B(1) in flight; A(0) staged; A(1) in regs ----
    #pragma unroll
    for (int c = 0; c < 4; ++c)
        GLOAD16(pB + (size_t)c * (64 * EDIM * 2), bR + bgOff + c * 1024);
    #pragma unroll
    for (int c = 0; c < 4; ++c)
        GLOAD16(pB + (size_t)c * (64 * EDIM * 2) + BK * 2, bN1 + bgOff + c * 1024);
    {
        float4 t0 = *(const float4*)pA;
        float4 t1 = *(const float4*)(pA + 4);
        short8 v;
        v[0] = (short)f2bf(t0.x); v[1] = (short)f2bf(t0.y);
        v[2] = (short)f2bf(t0.z); v[3] = (short)f2bf(t0.w);
        v[4] = (short)f2bf(t1.x); v[5] = (short)f2bf(t1.y);
        v[6] = (short)f2bf(t1.z); v[7] = (short)f2bf(t1.w);
        *(short8*)(aW ? (aR + aWoff) : 0) = v;   // aR = buf for kt=0
        rg[1][0] = *(const float4*)(pA + BK);
        rg[1][1] = *(const float4*)(pA + BK + 4);
    }
    sync_lgkm();

    // ---- main loop ----
    #pragma unroll 2
    for (int kt = 0; kt < NK; ++kt) {
        // 1. prefetch kt+2 (B -> LDS ring, A -> regs)
        if (kt + 2 < NK) {
            const char* ps = pB + (size_t)(kt + 2) * (BK * 2);
            #pragma unroll
            for (int c = 0; c < 4; ++c)
                GLOAD16(ps + (size_t)c * (64 * EDIM * 2), bN2 + bgOff + c * 1024);
            const float* pa = pA + (kt + 2) * BK;
            rg[kt & 1][0] = *(const float4*)pa;
            rg[kt & 1][1] = *(const float4*)(pa + 4);
        }
        // 2. compute current tile
        {
            short8 a[4], b[8];
            #pragma unroll
            for (int i = 0; i < 4; ++i)
                a[i] = *(const short8*)(aR + rgrp * 2048 + (wm * 64 + i * 16 + cif) * 16);
            #pragma unroll
            for (int j = 0; j < 8; ++j)
                b[j] = *(const short8*)(bR + rgrp * 8192 + (wn * 128 + j * 16 + cif) * 16);
            #pragma unroll
            for (int i = 0; i < 4; ++i)
                #pragma unroll
                for (int j = 0; j < 8; ++j)
                    acc[i][j] = __builtin_amdgcn_mfma_f32_16x16x32_bf16(a[i], b[j], acc[i][j], 0, 0, 0);
        }
        // 3. write-late A(kt+1): cvt forces counted vmcnt -> B(kt+1) retired too
        if (kt + 1 < NK) {
            float4 u0 = rg[(kt + 1) & 1][0];
            float4 u1 = rg[(kt + 1) & 1][1];
            short8 v;
            v[0] = (short)f2bf(u0.x); v[1] = (short)f2bf(u0.y);
            v[2] = (short)f2bf(u0.z); v[3] = (short)f2bf(u0.w);
            v[4] = (short)f2bf(u1.x); v[5] = (short)f2bf(u1.y);
            v[6] = (short)f2bf(u1.z); v[7] = (short)f2bf(u1.w);
            *(short8*)(aW + aWoff) = v;
            sync_lgkm();
        }
        // 4. rotate buffers
        { char* t = bR; bR = bN1; bN1 = bN2; bN2 = t; }
        { char* t = aR; aR = aW; aW = t; }
    }

    // ---- epilogue: relu(acc + bias) . Wfull, reduce over a ----
    const int bf  = m0 / PIX;
    const int thr = (bf + 1) * PIX;
    const int bfc = (bf + 1 < BATCH) ? bf + 1 : BATCH - 1;
    float wf[8], bs0[8], bs1[8];
    #pragma unroll
    for (int j = 0; j < 8; ++j) {
        int aj = wn * 128 + j * 16 + cif;
        wf[j]  = Wfull[aj];
        bs0[j] = bias[(size_t)bf  * ADIM + aj];
        bs1[j] = bias[(size_t)bfc * ADIM + aj];
    }
    #pragma unroll
    for (int i = 0; i < 4; ++i) {
        #pragma unroll
        for (int r = 0; r < 4; ++r) {
            int ml = wm * 64 + i * 16 + rgrp * 4 + r;
            int m  = m0 + ml;
            bool sec = (m >= thr);
            float s = 0.f;
            #pragma unroll
            for (int j = 0; j < 8; ++j) {
                float v = acc[i][j][r] + (sec ? bs1[j] : bs0[j]);
                s += fmaxf(v, 0.f) * wf[j];
            }
            s += __shfl_xor(s, 1);
            s += __shfl_xor(s, 2);
            s += __shfl_xor(s, 4);
            s += __shfl_xor(s, 8);
            if (cif == 0) red[wn][ml] = s;
        }
    }
    __syncthreads();
    if (tid < 128)
        att[m0 + tid] = red[0][tid] + red[1][tid] + red[2][tid] + red[3][tid];
}

// ---------------------------------------------------------------------------
// Kernel 3: softmax over p (b_full cancels in softmax)
// ---------------------------------------------------------------------------
__global__ __launch_bounds__(256) void softmax_kernel(const float* __restrict__ att,
                                                      float* __restrict__ alpha) {
    const int b = blockIdx.x;
    const int tid = threadIdx.x;
    const int lane = tid & 63, wid = tid >> 6;
    __shared__ float wred[4];

    float x = (tid < PIX) ? att[(size_t)b * PIX + tid] : -1e30f;
    float m = x;
    #pragma unroll
    for (int off = 32; off >= 1; off >>= 1) m = fmaxf(m, __shfl_xor(m, off));
    if (lane == 0) wred[wid] = m;
    __syncthreads();
    float gm = fmaxf(fmaxf(wred[0], wred[1]), fmaxf(wred[2], wred[3]));
    __syncthreads();

    float e = (tid < PIX) ? __expf(x - gm) : 0.f;
    float s = e;
    #pragma unroll
    for (int off = 32; off >= 1; off >>= 1) s += __shfl_xor(s, off);
    if (lane == 0) wred[wid] = s;
    __syncthreads();
    float gs = wred[0] + wred[1] + wred[2] + wred[3];

    if (tid < PIX) alpha[(size_t)b * PIX + tid] = e / gs;
}

// ---------------------------------------------------------------------------
// Kernel 4: out[b][e] = sum_p enc[b][p][e] * alpha[b][p]
// 4 blocks/batch x 128 threads x float4 (512 blocks total)
// ---------------------------------------------------------------------------
__global__ __launch_bounds__(128) void weighted_kernel(const float* __restrict__ enc,
                                                       const float* __restrict__ alpha,
                                                       float* __restrict__ out) {
    const int b = blockIdx.x >> 2;
    const int q = blockIdx.x & 3;
    const int tid = threadIdx.x;
    __shared__ float al[PIX];
    for (int i = tid; i < PIX; i += 128) al[i] = alpha[(size_t)b * PIX + i];
    __syncthreads();

    const int e = q * 512 + tid * 4;
    const float4* src = (const float4*)(enc + (size_t)b * PIX * EDIM + e);
    float ax = 0.f, ay = 0.f, az = 0.f, aw = 0.f;
    #pragma unroll 4
    for (int p = 0; p < PIX; p++) {
        float av = al[p];
        float4 v = src[(size_t)p * (EDIM / 4)];
        ax += av * v.x; ay += av * v.y; az += av * v.z; aw += av * v.w;
    }
    float4 o; o.x = ax; o.y = ay; o.z = az; o.w = aw;
    *(float4*)&out[(size_t)b * EDIM + e] = o;
}

// ---------------------------------------------------------------------------
extern "C" void kernel_launch(void* const* d_in, const int* in_sizes, int n_in,
                              void* d_out, int out_size, void* d_ws, size_t ws_size,
                              hipStream_t stream) {
    const float* enc   = (const float*)d_in[0];   // [128,196,2048]
    const float* dec   = (const float*)d_in[1];   // [128,512]
    const float* Wenc  = (const float*)d_in[2];   // [2048,512]
    const float* benc  = (const float*)d_in[3];   // [512]
    const float* Wdec  = (const float*)d_in[4];   // [512,512]
    const float* bdec  = (const float*)d_in[5];   // [512]
    const float* Wfull = (const float*)d_in[6];   // [512]
    // d_in[7] = b_full: constant shift, cancels in softmax

    float* out_awe   = (float*)d_out;                       // [128,2048]
    float* out_alpha = (float*)d_out + BATCH * EDIM;        // [128,196]

    char* ws = (char*)d_ws;
    unsigned short* WT = (unsigned short*)ws;                       // 2 MB bf16 [512][2048]
    float* bias = (float*)(ws + (size_t)ADIM * EDIM * 2);           // 256 KB [128][512]
    float* att  = (float*)(ws + (size_t)ADIM * EDIM * 2 + (size_t)BATCH * ADIM * 4); // 100 KB

    transpose_wenc<<<dim3(EDIM / 64, ADIM / 64), 256, 0, stream>>>(Wenc, WT);
    bias_kernel<<<BATCH / 4, 256, 0, stream>>>(dec, Wdec, benc, bdec, bias);
    gemm_att<<<MTOT / 128, 512, 0, stream>>>(enc, WT, bias, Wfull, att);
    softmax_kernel<<<BATCH, 256, 0, stream>>>(att, out_alpha);
    weighted_kernel<<<BATCH * 4, 128, 0, stream>>>(enc, out_alpha, out_awe);
}

// Round 3
// 132.939 us; speedup vs baseline: 2.0697x; 1.4297x over previous
//
#include <hip/hip_runtime.h>
#include <hip/hip_bf16.h>

// Problem dims (fixed by reference)
#define BATCH 128
#define PIX   196
#define EDIM  2048
#define DDIM  512
#define ADIM  512
#define MTOT  (BATCH*PIX)   // 25088
#define BK    32
#define NK    (EDIM/BK)     // 64

typedef __attribute__((ext_vector_type(8))) short short8;
typedef __attribute__((ext_vector_type(4))) float f32x4;

__device__ __forceinline__ unsigned short f2bf(float f) {
    union { float f; unsigned int u; } c; c.f = f;
    unsigned int u = c.u;
    u += 0x7fffu + ((u >> 16) & 1u);   // round-to-nearest-even
    return (unsigned short)(u >> 16);
}

__device__ __forceinline__ short8 cvt8(float4 a, float4 b) {
    short8 v;
    v[0] = (short)f2bf(a.x); v[1] = (short)f2bf(a.y);
    v[2] = (short)f2bf(a.z); v[3] = (short)f2bf(a.w);
    v[4] = (short)f2bf(b.x); v[5] = (short)f2bf(b.y);
    v[6] = (short)f2bf(b.z); v[7] = (short)f2bf(b.w);
    return v;
}

#define GLOAD16(gp, lp) __builtin_amdgcn_global_load_lds( \
    (const __attribute__((address_space(1))) void*)(gp),  \
    (__attribute__((address_space(3))) void*)(lp), 16, 0, 0)

#define MFMA16(a, b, c) __builtin_amdgcn_mfma_f32_16x16x32_bf16(a, b, c, 0, 0, 0)

// ---------------------------------------------------------------------------
// Kernel 0: pack W_enc [K=2048][A=512] fp32 into per-K-tile LDS images (bf16).
// Image kt (32 KB): byte addr = (n>>4)*1024 + (n&15)*64 + kc*16 holds bf16 of
// W_enc[kt*32 + kc*8 + d][n], d=0..7. gemm slurps each image linearly.
// ---------------------------------------------------------------------------
__global__ __launch_bounds__(256) void pack_wenc(const float* __restrict__ Wenc,
                                                 unsigned short* __restrict__ WTp) {
    __shared__ float f[32 * ADIM];   // 64 KB: rows k=kt*32..+31
    const int kt = blockIdx.x;
    const int tid = threadIdx.x;
    const float4* src = (const float4*)(Wenc + (size_t)kt * 32 * ADIM);
    float4* dst = (float4*)f;
    #pragma unroll
    for (int i = 0; i < 16; ++i)
        dst[tid + i * 256] = src[tid + i * 256];
    __syncthreads();
    for (int c = tid; c < 2048; c += 256) {
        int n  = ((c >> 6) << 4) + ((c >> 2) & 15);
        int kc = c & 3;
        short8 v;
        #pragma unroll
        for (int d = 0; d < 8; ++d)
            v[d] = (short)f2bf(f[(kc * 8 + d) * ADIM + n]);
        *(short8*)(WTp + (size_t)kt * 16384 + (size_t)c * 8) = v;
    }
}

// ---------------------------------------------------------------------------
// Kernel 1: bias[b][a] = sum_d dec[b][d]*Wdec[d][a] + b_dec[a] + b_enc[a]
// ---------------------------------------------------------------------------
__global__ __launch_bounds__(256) void bias_kernel(const float* __restrict__ dec,
                                                   const float* __restrict__ Wdec,
                                                   const float* __restrict__ b_enc,
                                                   const float* __restrict__ b_dec,
                                                   float* __restrict__ bias) {
    __shared__ float ds[4 * DDIM];
    const int b0 = blockIdx.x * 4;
    for (int i = threadIdx.x; i < 4 * DDIM; i += 256)
        ds[i] = dec[(size_t)b0 * DDIM + i];
    __syncthreads();
    const int a0 = threadIdx.x * 2;
    float acc0[4] = {0.f, 0.f, 0.f, 0.f};
    float acc1[4] = {0.f, 0.f, 0.f, 0.f};
    for (int d = 0; d < DDIM; d++) {
        float2 w = *(const float2*)&Wdec[(size_t)d * ADIM + a0];
        #pragma unroll
        for (int bi = 0; bi < 4; bi++) {
            float dv = ds[bi * DDIM + d];
            acc0[bi] += dv * w.x;
            acc1[bi] += dv * w.y;
        }
    }
    float be0 = b_enc[a0] + b_dec[a0];
    float be1 = b_enc[a0 + 1] + b_dec[a0 + 1];
    #pragma unroll
    for (int bi = 0; bi < 4; bi++) {
        bias[(size_t)(b0 + bi) * ADIM + a0]     = acc0[bi] + be0;
        bias[(size_t)(b0 + bi) * ADIM + a0 + 1] = acc1[bi] + be1;
    }
}

// ---------------------------------------------------------------------------
// Kernel 2: fused att1 GEMM + relu + dot(W_full) -> att[m]
// Tile 128M x 512N x 32K, 8 waves (2M x 4N), wave tile 64x128.
// B: linear gload_lds of pre-packed 32KB images, 3-deep ring.
// A: global->reg->cvt->ds_write, 2-deep. Counted vmcnt(6) BEFORE each barrier
// (the barrier publishes kt+1; kt+2's 6 loads stay in flight). No drains.
// All LDS reads/writes are contiguous-1KB-per-wave (conflict-free).
// ---------------------------------------------------------------------------
__global__ __launch_bounds__(512, 2) void gemm_att(const float* __restrict__ enc,
                                                   const unsigned short* __restrict__ WTp,
                                                   const float* __restrict__ bias,
                                                   const float* __restrict__ Wfull,
                                                   float* __restrict__ att) {
    __shared__ __align__(16) char ldsA[2][8192];
    __shared__ __align__(16) char ldsB[3][32768];
    __shared__ float red[4][128];

    const int tid  = threadIdx.x;
    const int lane = tid & 63;
    const int wid  = tid >> 6;          // 0..7
    const int wm   = wid >> 2;          // 0..1
    const int wn   = wid & 3;           // 0..3
    const int cif  = lane & 15;
    const int rgrp = lane >> 4;
    const int loff = cif * 64 + rgrp * 16;   // within-1KB lane offset for frag reads
    const int m0   = blockIdx.x * 128;

    // A: thread -> (row = tid>>2, kc = tid&3); 32B global read, 16B LDS write
    const float* pA = enc + (size_t)(m0 + (tid >> 2)) * EDIM + (tid & 3) * 8;
    const unsigned aWoff = (unsigned)(wid * 1024 + lane * 16);   // linear per wave
    // B: linear image copy; wave wid owns bytes [wid*4096, wid*4096+4096)
    const char* pB = (const char*)WTp + (size_t)wid * 4096 + (size_t)lane * 16;
    const unsigned bgOff = (unsigned)(wid * 4096);

    char* aR = ldsA[0]; char* aW = ldsA[1];
    char* bR = ldsB[0]; char* bN1 = ldsB[1]; char* bN2 = ldsB[2];

    f32x4 acc[4][8] = {};
    float4 rg[2][2];

    // ---- prologue: order A0,A1 then B0,B1 so cvt(A0) doesn't drain B ----
    float4 t0 = *(const float4*)pA;
    float4 t1 = *(const float4*)(pA + 4);
    rg[1][0] = *(const float4*)(pA + BK);
    rg[1][1] = *(const float4*)(pA + BK + 4);
    #pragma unroll
    for (int c = 0; c < 4; ++c)
        GLOAD16(pB + c * 1024, bR + bgOff + c * 1024);
    #pragma unroll
    for (int c = 0; c < 4; ++c)
        GLOAD16(pB + 32768 + c * 1024, bN1 + bgOff + c * 1024);
    *(short8*)(aR + aWoff) = cvt8(t0, t1);
    asm volatile("s_waitcnt vmcnt(4)" ::: "memory");   // B0 done; B1 stays in flight
    asm volatile("s_waitcnt lgkmcnt(0)" ::: "memory");
    __builtin_amdgcn_s_barrier();

    // ---- main loop: kt = 0 .. NK-3 ----
    #pragma unroll 2
    for (int kt = 0; kt < NK - 2; ++kt) {
        // 1. issue kt+2 prefetch (B -> LDS ring, A -> regs)
        const char* ps = pB + (size_t)(kt + 2) * 32768;
        #pragma unroll
        for (int c = 0; c < 4; ++c)
            GLOAD16(ps + c * 1024, bN2 + bgOff + c * 1024);
        {
            const float* pa = pA + (kt + 2) * BK;
            rg[kt & 1][0] = *(const float4*)pa;
            rg[kt & 1][1] = *(const float4*)(pa + 4);
        }
        // 2. compute kt (published by previous barrier)
        {
            short8 a[4], b[8];
            #pragma unroll
            for (int i = 0; i < 4; ++i)
                a[i] = *(const short8*)(aR + (wm * 4 + i) * 1024 + loff);
            #pragma unroll
            for (int j = 0; j < 8; ++j)
                b[j] = *(const short8*)(bR + (wn * 8 + j) * 1024 + loff);
            __builtin_amdgcn_s_setprio(1);
            #pragma unroll
            for (int i = 0; i < 4; ++i)
                #pragma unroll
                for (int j = 0; j < 8; ++j)
                    acc[i][j] = MFMA16(a[i], b[j], acc[i][j]);
            __builtin_amdgcn_s_setprio(0);
        }
        // 3. cvt+write A(kt+1) (auto counted vmcnt(6) for rg)
        *(short8*)(aW + aWoff) = cvt8(rg[(kt + 1) & 1][0], rg[(kt + 1) & 1][1]);
        // 4. publish kt+1: own loads for kt+1 retired BEFORE the barrier;
        //    kt+2's 6 loads remain in flight.
        asm volatile("s_waitcnt vmcnt(6)" ::: "memory");
        asm volatile("s_waitcnt lgkmcnt(0)" ::: "memory");
        __builtin_amdgcn_s_barrier();
        { char* t = bR; bR = bN1; bN1 = bN2; bN2 = t; }
        { char* t = aR; aR = aW; aW = t; }
    }

    // ---- peeled kt = NK-2 ----
    {
        short8 a[4], b[8];
        #pragma unroll
        for (int i = 0; i < 4; ++i)
            a[i] = *(const short8*)(aR + (wm * 4 + i) * 1024 + loff);
        #pragma unroll
        for (int j = 0; j < 8; ++j)
            b[j] = *(const short8*)(bR + (wn * 8 + j) * 1024 + loff);
        __builtin_amdgcn_s_setprio(1);
        #pragma unroll
        for (int i = 0; i < 4; ++i)
            #pragma unroll
            for (int j = 0; j < 8; ++j)
                acc[i][j] = MFMA16(a[i], b[j], acc[i][j]);
        __builtin_amdgcn_s_setprio(0);
        *(short8*)(aW + aWoff) = cvt8(rg[(NK - 1) & 1][0], rg[(NK - 1) & 1][1]);
        asm volatile("s_waitcnt vmcnt(0)" ::: "memory");
        asm volatile("s_waitcnt lgkmcnt(0)" ::: "memory");
        __builtin_amdgcn_s_barrier();
        { char* t = bR; bR = bN1; bN1 = bN2; bN2 = t; }
        { char* t = aR; aR = aW; aW = t; }
    }
    // ---- peeled kt = NK-1 ----
    {
        short8 a[4], b[8];
        #pragma unroll
        for (int i = 0; i < 4; ++i)
            a[i] = *(const short8*)(aR + (wm * 4 + i) * 1024 + loff);
        #pragma unroll
        for (int j = 0; j < 8; ++j)
            b[j] = *(const short8*)(bR + (wn * 8 + j) * 1024 + loff);
        #pragma unroll
        for (int i = 0; i < 4; ++i)
            #pragma unroll
            for (int j = 0; j < 8; ++j)
                acc[i][j] = MFMA16(a[i], b[j], acc[i][j]);
    }

    // ---- epilogue: relu(acc + bias) . Wfull, reduce over a ----
    const int bf  = m0 / PIX;
    const int thr = (bf + 1) * PIX;
    const int bfc = (bf + 1 < BATCH) ? bf + 1 : BATCH - 1;
    float wf[8], bs0[8], bs1[8];
    #pragma unroll
    for (int j = 0; j < 8; ++j) {
        int aj = wn * 128 + j * 16 + cif;
        wf[j]  = Wfull[aj];
        bs0[j] = bias[(size_t)bf  * ADIM + aj];
        bs1[j] = bias[(size_t)bfc * ADIM + aj];
    }
    #pragma unroll
    for (int i = 0; i < 4; ++i) {
        #pragma unroll
        for (int r = 0; r < 4; ++r) {
            int ml = wm * 64 + i * 16 + rgrp * 4 + r;
            int m  = m0 + ml;
            bool sec = (m >= thr);
            float s = 0.f;
            #pragma unroll
            for (int j = 0; j < 8; ++j) {
                float v = acc[i][j][r] + (sec ? bs1[j] : bs0[j]);
                s += fmaxf(v, 0.f) * wf[j];
            }
            s += __shfl_xor(s, 1);
            s += __shfl_xor(s, 2);
            s += __shfl_xor(s, 4);
            s += __shfl_xor(s, 8);
            if (cif == 0) red[wn][ml] = s;
        }
    }
    __syncthreads();
    if (tid < 128)
        att[m0 + tid] = red[0][tid] + red[1][tid] + red[2][tid] + red[3][tid];
}

// ---------------------------------------------------------------------------
// Kernel 3: softmax over p (b_full cancels in softmax)
// ---------------------------------------------------------------------------
__global__ __launch_bounds__(256) void softmax_kernel(const float* __restrict__ att,
                                                      float* __restrict__ alpha) {
    const int b = blockIdx.x;
    const int tid = threadIdx.x;
    const int lane = tid & 63, wid = tid >> 6;
    __shared__ float wred[4];

    float x = (tid < PIX) ? att[(size_t)b * PIX + tid] : -1e30f;
    float m = x;
    #pragma unroll
    for (int off = 32; off >= 1; off >>= 1) m = fmaxf(m, __shfl_xor(m, off));
    if (lane == 0) wred[wid] = m;
    __syncthreads();
    float gm = fmaxf(fmaxf(wred[0], wred[1]), fmaxf(wred[2], wred[3]));
    __syncthreads();

    float e = (tid < PIX) ? __expf(x - gm) : 0.f;
    float s = e;
    #pragma unroll
    for (int off = 32; off >= 1; off >>= 1) s += __shfl_xor(s, off);
    if (lane == 0) wred[wid] = s;
    __syncthreads();
    float gs = wred[0] + wred[1] + wred[2] + wred[3];

    if (tid < PIX) alpha[(size_t)b * PIX + tid] = e / gs;
}

// ---------------------------------------------------------------------------
// Kernel 4: out[b][e] = sum_p enc[b][p][e] * alpha[b][p]
// ---------------------------------------------------------------------------
__global__ __launch_bounds__(128) void weighted_kernel(const float* __restrict__ enc,
                                                       const float* __restrict__ alpha,
                                                       float* __restrict__ out) {
    const int b = blockIdx.x >> 2;
    const int q = blockIdx.x & 3;
    const int tid = threadIdx.x;
    __shared__ float al[PIX];
    for (int i = tid; i < PIX; i += 128) al[i] = alpha[(size_t)b * PIX + i];
    __syncthreads();

    const int e = q * 512 + tid * 4;
    const float4* src = (const float4*)(enc + (size_t)b * PIX * EDIM + e);
    float ax = 0.f, ay = 0.f, az = 0.f, aw = 0.f;
    #pragma unroll 4
    for (int p = 0; p < PIX; p++) {
        float av = al[p];
        float4 v = src[(size_t)p * (EDIM / 4)];
        ax += av * v.x; ay += av * v.y; az += av * v.z; aw += av * v.w;
    }
    float4 o; o.x = ax; o.y = ay; o.z = az; o.w = aw;
    *(float4*)&out[(size_t)b * EDIM + e] = o;
}

// ---------------------------------------------------------------------------
extern "C" void kernel_launch(void* const* d_in, const int* in_sizes, int n_in,
                              void* d_out, int out_size, void* d_ws, size_t ws_size,
                              hipStream_t stream) {
    const float* enc   = (const float*)d_in[0];   // [128,196,2048]
    const float* dec   = (const float*)d_in[1];   // [128,512]
    const float* Wenc  = (const float*)d_in[2];   // [2048,512]
    const float* benc  = (const float*)d_in[3];   // [512]
    const float* Wdec  = (const float*)d_in[4];   // [512,512]
    const float* bdec  = (const float*)d_in[5];   // [512]
    const float* Wfull = (const float*)d_in[6];   // [512]
    // d_in[7] = b_full: constant shift, cancels in softmax

    float* out_awe   = (float*)d_out;                       // [128,2048]
    float* out_alpha = (float*)d_out + BATCH * EDIM;        // [128,196]

    char* ws = (char*)d_ws;
    unsigned short* WTp = (unsigned short*)ws;                      // 2 MB packed images
    float* bias = (float*)(ws + (size_t)ADIM * EDIM * 2);           // 256 KB [128][512]
    float* att  = (float*)(ws + (size_t)ADIM * EDIM * 2 + (size_t)BATCH * ADIM * 4);

    pack_wenc<<<NK, 256, 0, stream>>>(Wenc, WTp);
    bias_kernel<<<BATCH / 4, 256, 0, stream>>>(dec, Wdec, benc, bdec, bias);
    gemm_att<<<MTOT / 128, 512, 0, stream>>>(enc, WTp, bias, Wfull, att);
    softmax_kernel<<<BATCH, 256, 0, stream>>>(att, out_alpha);
    weighted_kernel<<<BATCH * 4, 128, 0, stream>>>(enc, out_alpha, out_awe);
}